// Round 1
// baseline (5836.417 us; speedup 1.0000x reference)
//
#include <hip/hip_runtime.h>

// ---------------- problem constants ----------------
#define T_SEQ 80
#define NB    5120
#define HID   256
#define G4    1024
#define NVOC  100

// ---------------- ws layout (bytes) ----------------
#define OFF_TABLE0 0u          // 100*1024*4        = 409600
#define OFF_BIAS1  409600u     // 1024*4            = 4096
#define OFF_BP0    413696u     // 8*8*8*64*8*2      = 524288
#define OFF_BP1    937984u     // 16*16*4*64*8*2    = 1048576
#define OFF_RING   1986560u    // 2*5120*256*2      = 5242880   (ys0, 2 slots)
#define OFF_H1R    7229440u    // 2*5120*256*2      = 5242880   (h1 bf16, 2 slots)
#define OFF_H1F    12472320u   // 5120*256*4        = 5242880   (h1 f32, last step)
#define OFF_BAR    17715200u   // 4                 (grid barrier counter)

// LDS: B0 (64KB) + B1 (64KB) + Abuf (320 rows * 80B = 25600)
#define SMEM_BYTES (65536 + 65536 + 25600)

typedef float  f32x4  __attribute__((ext_vector_type(4)));
typedef __bf16 bf16x8 __attribute__((ext_vector_type(8)));

// column permutation: n' -> original gate-major row index (i,f,g,o blocks of 256)
// n' layout: [group64 = 16 h-dims][gate(4)][16 h-offsets]
__device__ __host__ __forceinline__ int colmap(int np) {
  int gate = (np >> 4) & 3;
  int j    = ((np >> 6) << 4) | (np & 15);
  return gate * 256 + j;
}

__device__ __forceinline__ unsigned short f2bf(float f) {
  unsigned int u = __float_as_uint(f);
  u += 0x7fffu + ((u >> 16) & 1u);   // round-to-nearest-even
  return (unsigned short)(u >> 16);
}

__device__ __forceinline__ float sigm(float x) {
  x = fminf(fmaxf(x, -20.f), 20.f);
  return 1.f / (1.f + __expf(-x));
}
__device__ __forceinline__ float tanh_(float x) {
  x = fminf(fmaxf(x, -10.f), 10.f);
  float e = __expf(2.f * x);
  return (e - 1.f) / (e + 1.f);
}

// ---------------- prep: tables + bf16 weight repack ----------------
// total elements: table0 102400 | bias1 1024 | Bp0 262144 | Bp1 524288 = 889856
__global__ void prep_kernel(const float* __restrict__ emb,
                            const float* __restrict__ w_ih0, const float* __restrict__ w_hh0,
                            const float* __restrict__ b_ih0, const float* __restrict__ b_hh0,
                            const float* __restrict__ w_ih1, const float* __restrict__ w_hh1,
                            const float* __restrict__ b_ih1, const float* __restrict__ b_hh1,
                            float* __restrict__ table0, float* __restrict__ bias1,
                            unsigned short* __restrict__ Bp0, unsigned short* __restrict__ Bp1) {
  int idx = blockIdx.x * 256 + threadIdx.x;
  if (idx < 102400) {
    int v = idx >> 10, np = idx & 1023;
    int row = colmap(np);
    float s = b_ih0[row] + b_hh0[row];
#pragma unroll
    for (int e = 0; e < 8; ++e) s = fmaf(emb[v * 8 + e], w_ih0[row * 8 + e], s);
    table0[idx] = s;
  } else if (idx < 103424) {
    int np = idx - 102400;
    int row = colmap(np);
    bias1[np] = b_ih1[row] + b_hh1[row];
  } else if (idx < 365568) {
    // Bp0: [ni(8)][kc(8)][nf(8)][lane(64)][i(8)]  (w_hh0, K=256)
    int i2 = idx - 103424;
    int i = i2 & 7, lane = (i2 >> 3) & 63, nf = (i2 >> 9) & 7, kc = (i2 >> 12) & 7, ni = i2 >> 15;
    int k  = kc * 32 + ((lane >> 4) << 3) + i;
    int np = ni * 128 + nf * 16 + (lane & 15);
    int row = colmap(np);
    Bp0[i2] = f2bf(w_hh0[row * 256 + k]);
  } else if (idx < 889856) {
    // Bp1: [ni(16)][kc(16)][nf(4)][lane(64)][i(8)]  ([w_ih1 | w_hh1], K=512)
    int i2 = idx - 365568;
    int i = i2 & 7, lane = (i2 >> 3) & 63, nf = (i2 >> 9) & 3, kc = (i2 >> 11) & 15, ni = i2 >> 15;
    int k  = kc * 32 + ((lane >> 4) << 3) + i;
    int np = ni * 64 + nf * 16 + (lane & 15);
    int row = colmap(np);
    float val = (k < 256) ? w_ih1[row * 256 + k] : w_hh1[row * 256 + (k - 256)];
    Bp1[i2] = f2bf(val);
  }
}

// ---------------- grid barrier (all 256 blocks co-resident: 1 block/CU) ----------------
__device__ __forceinline__ void gbar(int* cnt, int target) {
  __syncthreads();
  if (threadIdx.x == 0) {
    __threadfence();
    __hip_atomic_fetch_add(cnt, 1, __ATOMIC_RELEASE, __HIP_MEMORY_SCOPE_AGENT);
    while (__hip_atomic_load(cnt, __ATOMIC_ACQUIRE, __HIP_MEMORY_SCOPE_AGENT) < target)
      __builtin_amdgcn_s_sleep(2);
    __threadfence();
  }
  __syncthreads();
}

// ---------------- fused persistent LSTM kernel ----------------
// grid = 256 blocks (1/CU), 256 threads (4 waves).
// Layer0 tiling: 32x8 blocks of [160 x 128], waves 2x2 of [80 x 64]
// Layer1 tiling: 16x16 blocks of [320 x 64], waves 4x1 of [80 x 64]
// wave n-extent 64 = 4 gate-fragments of 16 h-dims -> lane-local LSTM cell update.
__global__ __launch_bounds__(256, 1) void lstm_fused(
    const int* __restrict__ x,
    const float* __restrict__ table0, const float* __restrict__ bias1,
    const unsigned short* __restrict__ Bp0, const unsigned short* __restrict__ Bp1,
    unsigned short* __restrict__ ring,   // ys0, 2 slots
    unsigned short* __restrict__ h1r,    // h1 bf16, 2 slots
    float* __restrict__ h1f,
    const float* __restrict__ dec_w, const float* __restrict__ dec_b,
    float* __restrict__ out, int* __restrict__ bar) {
  extern __shared__ char smem[];
  unsigned short* B0 = (unsigned short*)smem;            // [8 kc][8 nf][64][8]
  unsigned short* B1 = (unsigned short*)(smem + 65536);  // [16 kc][4 nf][64][8]
  char* Abuf = smem + 131072;                            // rows padded to 80B

  const int tid  = threadIdx.x;
  const int lane = tid & 63;
  const int wid  = tid >> 6;
  const int l15  = lane & 15;
  const int lhi  = lane >> 4;
  const int bid  = blockIdx.x;

  const int mi0 = bid >> 3, ni0 = bid & 7;
  const int rows0 = mi0 * 160;
  const int wx0 = wid & 1, wy0 = wid >> 1;
  const int rw0 = wx0 * 80;

  const int mi1 = bid >> 4, ni1 = bid & 15;
  const int rows1 = mi1 * 320;
  const int rw1 = wid * 80;

  // stage both layers' weight tiles into LDS once (resident for all 80 steps)
  {
    const uint4* s0 = (const uint4*)(Bp0 + ni0 * 32768);
    uint4* d0 = (uint4*)B0;
    for (int i = tid; i < 4096; i += 256) d0[i] = s0[i];
    const uint4* s1 = (const uint4*)(Bp1 + ni1 * 32768);
    uint4* d1 = (uint4*)B1;
    for (int i = tid; i < 4096; i += 256) d1[i] = s1[i];
  }
  __syncthreads();

  f32x4 acc[5][4];
  float c0r[20], c1r[20];
  int ep = 0;

  for (int t = 0; t < T_SEQ; ++t) {
    // ================= layer 0 =================
#pragma unroll
    for (int m = 0; m < 5; ++m)
#pragma unroll
      for (int nf = 0; nf < 4; ++nf) acc[m][nf] = (f32x4)0.f;

    if (t > 0) {
      const unsigned short* Ar = ring + ((t - 1) & 1) * (NB * HID);
      for (int kc = 0; kc < 8; ++kc) {
        __syncthreads();
        for (int u = tid; u < 640; u += 256) {       // 160 rows x 4 x 16B
          int r = u >> 2, ku = u & 3;
          uint4 v = *(const uint4*)(Ar + (rows0 + r) * 256 + kc * 32 + ku * 8);
          *(uint4*)(Abuf + r * 80 + ku * 16) = v;
        }
        __syncthreads();
        bf16x8 a[5];
#pragma unroll
        for (int m = 0; m < 5; ++m)
          a[m] = *(const bf16x8*)(Abuf + (rw0 + m * 16 + l15) * 80 + lhi * 16);
#pragma unroll
        for (int nf = 0; nf < 4; ++nf) {
          bf16x8 b = *(const bf16x8*)(B0 + ((kc * 8 + wy0 * 4 + nf) * 64 + lane) * 8);
#pragma unroll
          for (int m = 0; m < 5; ++m)
            acc[m][nf] = __builtin_amdgcn_mfma_f32_16x16x32_bf16(a[m], b, acc[m][nf], 0, 0, 0);
        }
      }
    }
    // epilogue L0: gates -> (c,h); c in regs; h -> ring[t&1] (bf16)
    {
      unsigned short* rw_ = ring + (t & 1) * (NB * HID);
      const int jg = ni0 * 32 + wy0 * 16 + l15;
      const int tb_base = ni0 * 128 + wy0 * 64 + l15;
#pragma unroll
      for (int m = 0; m < 5; ++m) {
#pragma unroll
        for (int r = 0; r < 4; ++r) {
          int rowg = rows0 + rw0 + m * 16 + lhi * 4 + r;
          int v = x[t * NB + rowg];
          const float* tb = table0 + v * 1024 + tb_base;
          float gi = acc[m][0][r] + tb[0];
          float gf = acc[m][1][r] + tb[16];
          float gg = acc[m][2][r] + tb[32];
          float go = acc[m][3][r] + tb[48];
          float cold = (t > 0) ? c0r[m * 4 + r] : 0.f;
          float cn = sigm(gf) * cold + sigm(gi) * tanh_(gg);
          c0r[m * 4 + r] = cn;
          float h = sigm(go) * tanh_(cn);
          rw_[rowg * 256 + jg] = f2bf(h);
        }
      }
    }
    ++ep;
    gbar(bar, ep * 256);   // single barrier per step orders everything (see hazard analysis)

    // ================= layer 1 =================
#pragma unroll
    for (int m = 0; m < 5; ++m)
#pragma unroll
      for (int nf = 0; nf < 4; ++nf) acc[m][nf] = (f32x4)0.f;

    const unsigned short* ringr = ring + (t & 1) * (NB * HID);
    const unsigned short* h1old = h1r + ((t - 1) & 1) * (NB * HID);
    int kcN = (t == 0) ? 8 : 16;   // t==0: h1=0, skip h-part
    for (int kc = 0; kc < kcN; ++kc) {
      __syncthreads();
      const unsigned short* Asrc = (kc < 8) ? ringr : h1old;
      int kof = (kc & 7) * 32;
      for (int u = tid; u < 1280; u += 256) {        // 320 rows x 4 x 16B
        int r = u >> 2, ku = u & 3;
        uint4 v = *(const uint4*)(Asrc + (rows1 + r) * 256 + kof + ku * 8);
        *(uint4*)(Abuf + r * 80 + ku * 16) = v;
      }
      __syncthreads();
      bf16x8 a[5];
#pragma unroll
      for (int m = 0; m < 5; ++m)
        a[m] = *(const bf16x8*)(Abuf + (rw1 + m * 16 + l15) * 80 + lhi * 16);
#pragma unroll
      for (int nf = 0; nf < 4; ++nf) {
        bf16x8 b = *(const bf16x8*)(B1 + ((kc * 4 + nf) * 64 + lane) * 8);
#pragma unroll
        for (int m = 0; m < 5; ++m)
          acc[m][nf] = __builtin_amdgcn_mfma_f32_16x16x32_bf16(a[m], b, acc[m][nf], 0, 0, 0);
      }
    }
    // epilogue L1
    {
      unsigned short* h1w = h1r + (t & 1) * (NB * HID);
      const int jg = ni1 * 16 + l15;
      const float* bb = bias1 + ni1 * 64 + l15;
#pragma unroll
      for (int m = 0; m < 5; ++m) {
#pragma unroll
        for (int r = 0; r < 4; ++r) {
          int rowg = rows1 + rw1 + m * 16 + lhi * 4 + r;
          float gi = acc[m][0][r] + bb[0];
          float gf = acc[m][1][r] + bb[16];
          float gg = acc[m][2][r] + bb[32];
          float go = acc[m][3][r] + bb[48];
          float cold = (t > 0) ? c1r[m * 4 + r] : 0.f;
          float cn = sigm(gf) * cold + sigm(gi) * tanh_(gg);
          c1r[m * 4 + r] = cn;
          float h = sigm(go) * tanh_(cn);
          h1w[rowg * 256 + jg] = f2bf(h);
          if (t == T_SEQ - 1) h1f[rowg * 256 + jg] = h;  // f32 for decoder
        }
      }
    }
    // no trailing barrier needed: next iteration's single barrier orders all hazards
  }

  ++ep;
  gbar(bar, ep * 256);   // h1f complete

  // ================= decoder: out[64][100] = flat[64][20480] @ dec_w^T + dec_b =======
  if (bid < NVOC) {
    const int v = bid;
    float dacc[64];
#pragma unroll
    for (int r = 0; r < 64; ++r) dacc[r] = 0.f;
    for (int q = tid; q < 20480; q += 256) {
      float w = dec_w[(size_t)v * 20480 + q];
      const float* fp = h1f + q;
#pragma unroll
      for (int r = 0; r < 64; ++r) dacc[r] = fmaf(fp[r * 20480], w, dacc[r]);
    }
    float* red = (float*)(smem + 131072);
#pragma unroll
    for (int r = 0; r < 64; ++r) {
      float s = dacc[r];
      for (int off = 32; off > 0; off >>= 1) s += __shfl_down(s, off, 64);
      if (lane == 0) red[wid * 64 + r] = s;
    }
    __syncthreads();
    if (tid < 64) {
      float s = red[tid] + red[64 + tid] + red[128 + tid] + red[192 + tid];
      out[tid * 100 + v] = s + dec_b[v];
    }
  }
}

// ---------------- host launch ----------------
extern "C" void kernel_launch(void* const* d_in, const int* in_sizes, int n_in,
                              void* d_out, int out_size, void* d_ws, size_t ws_size,
                              hipStream_t stream) {
  const int*   x     = (const int*)d_in[0];
  const float* emb   = (const float*)d_in[1];
  const float* w_ih0 = (const float*)d_in[2];
  const float* w_hh0 = (const float*)d_in[3];
  const float* b_ih0 = (const float*)d_in[4];
  const float* b_hh0 = (const float*)d_in[5];
  const float* w_ih1 = (const float*)d_in[6];
  const float* w_hh1 = (const float*)d_in[7];
  const float* b_ih1 = (const float*)d_in[8];
  const float* b_hh1 = (const float*)d_in[9];
  const float* dec_w = (const float*)d_in[10];
  const float* dec_b = (const float*)d_in[11];
  float* out = (float*)d_out;
  char* ws = (char*)d_ws;

  float*          table0 = (float*)(ws + OFF_TABLE0);
  float*          bias1  = (float*)(ws + OFF_BIAS1);
  unsigned short* Bp0    = (unsigned short*)(ws + OFF_BP0);
  unsigned short* Bp1    = (unsigned short*)(ws + OFF_BP1);
  unsigned short* ring   = (unsigned short*)(ws + OFF_RING);
  unsigned short* h1r    = (unsigned short*)(ws + OFF_H1R);
  float*          h1f    = (float*)(ws + OFF_H1F);
  int*            bar    = (int*)(ws + OFF_BAR);

  hipMemsetAsync(bar, 0, 4, stream);
  prep_kernel<<<3476, 256, 0, stream>>>(emb, w_ih0, w_hh0, b_ih0, b_hh0,
                                        w_ih1, w_hh1, b_ih1, b_hh1,
                                        table0, bias1, Bp0, Bp1);
  hipFuncSetAttribute((const void*)lstm_fused,
                      hipFuncAttributeMaxDynamicSharedMemorySize, SMEM_BYTES);
  lstm_fused<<<256, 256, SMEM_BYTES, stream>>>(x, table0, bias1, Bp0, Bp1,
                                               ring, h1r, h1f, dec_w, dec_b, out, bar);
}

// Round 2
// 5155.705 us; speedup vs baseline: 1.1320x; 1.1320x over previous
//
#include <hip/hip_runtime.h>

// ---------------- problem constants ----------------
#define T_SEQ 80
#define NB    5120
#define HID   256
#define NBH   (NB * HID)
#define NVOC  100

// ---------------- ws layout (bytes) ----------------
#define OFF_TABLE0 0u          // 100*1024*4        = 409600
#define OFF_BIAS1  409600u     // 1024*4            = 4096
#define OFF_BP0    413696u     // 8*8*8*64*8*2      = 524288
#define OFF_BP1    937984u     // 16*16*4*64*8*2    = 1048576
#define OFF_RING   1986560u    // 2*5120*256*2      = 5242880   (ys0, 2 slots)
#define OFF_H1R    7229440u    // 2*5120*256*2      = 5242880   (h1 bf16, 2 slots)
#define OFF_H1F    12472320u   // 5120*256*4        = 5242880   (h1 f32, last step)
#define OFF_FLAGS  17715200u   // 256 flags * 128B  = 32768
#define OFF_EPOCH  17747968u   // 4

// LDS: B0 (64KB) + B1 (64KB); decoder reduction buffer reuses B0 area
#define SMEM_BYTES 131072

typedef float  f32x4  __attribute__((ext_vector_type(4)));
typedef __bf16 bf16x8 __attribute__((ext_vector_type(8)));

// column permutation: n' -> original gate-major row index (i,f,g,o blocks of 256)
__device__ __host__ __forceinline__ int colmap(int np) {
  int gate = (np >> 4) & 3;
  int j    = ((np >> 6) << 4) | (np & 15);
  return gate * 256 + j;
}

__device__ __forceinline__ unsigned short f2bf(float f) {
  unsigned int u = __float_as_uint(f);
  u += 0x7fffu + ((u >> 16) & 1u);   // round-to-nearest-even
  return (unsigned short)(u >> 16);
}

__device__ __forceinline__ float sigm(float x) {
  x = fminf(fmaxf(x, -20.f), 20.f);
  return 1.f / (1.f + __expf(-x));
}
__device__ __forceinline__ float tanh_(float x) {
  x = fminf(fmaxf(x, -10.f), 10.f);
  float e = __expf(2.f * x);
  return (e - 1.f) / (e + 1.f);
}

// ---------------- prep: tables + bf16 weight repack ----------------
__global__ void prep_kernel(const float* __restrict__ emb,
                            const float* __restrict__ w_ih0, const float* __restrict__ w_hh0,
                            const float* __restrict__ b_ih0, const float* __restrict__ b_hh0,
                            const float* __restrict__ w_ih1, const float* __restrict__ w_hh1,
                            const float* __restrict__ b_ih1, const float* __restrict__ b_hh1,
                            float* __restrict__ table0, float* __restrict__ bias1,
                            unsigned short* __restrict__ Bp0, unsigned short* __restrict__ Bp1) {
  int idx = blockIdx.x * 256 + threadIdx.x;
  if (idx < 102400) {
    int v = idx >> 10, np = idx & 1023;
    int row = colmap(np);
    float s = b_ih0[row] + b_hh0[row];
#pragma unroll
    for (int e = 0; e < 8; ++e) s = fmaf(emb[v * 8 + e], w_ih0[row * 8 + e], s);
    table0[idx] = s;
  } else if (idx < 103424) {
    int np = idx - 102400;
    int row = colmap(np);
    bias1[np] = b_ih1[row] + b_hh1[row];
  } else if (idx < 365568) {
    // Bp0: [ni(8)][kc(8)][nf(8)][lane(64)][i(8)]  (w_hh0, K=256)
    int i2 = idx - 103424;
    int i = i2 & 7, lane = (i2 >> 3) & 63, nf = (i2 >> 9) & 7, kc = (i2 >> 12) & 7, ni = i2 >> 15;
    int k  = kc * 32 + ((lane >> 4) << 3) + i;
    int np = ni * 128 + nf * 16 + (lane & 15);
    int row = colmap(np);
    Bp0[i2] = f2bf(w_hh0[row * 256 + k]);
  } else if (idx < 889856) {
    // Bp1: [ni(16)][kc(16)][nf(4)][lane(64)][i(8)]  ([w_ih1 | w_hh1], K=512)
    int i2 = idx - 365568;
    int i = i2 & 7, lane = (i2 >> 3) & 63, nf = (i2 >> 9) & 3, kc = (i2 >> 11) & 15, ni = i2 >> 15;
    int k  = kc * 32 + ((lane >> 4) << 3) + i;
    int np = ni * 64 + nf * 16 + (lane & 15);
    int row = colmap(np);
    float val = (k < 256) ? w_ih1[row * 256 + k] : w_hh1[row * 256 + (k - 256)];
    Bp1[i2] = f2bf(val);
  }
}

// ---------------- distributed-flag grid barrier (256 co-resident blocks) ----------------
// Arrivals: each block release-stores `ep` to its own 128B-padded flag (no RMW contention).
// Block 0: 256 threads poll the 256 flags in parallel, then publish `ep` to the epoch word.
// Others: spin (read-only) on the epoch word.
__device__ __forceinline__ void gbar(int* flags, int* epoch, int ep) {
  __syncthreads();
  const int tid = threadIdx.x;
  if (blockIdx.x == 0) {
    if (tid == 0) {
      __threadfence();
      __hip_atomic_store(&flags[0], ep, __ATOMIC_RELEASE, __HIP_MEMORY_SCOPE_AGENT);
    }
    int* f = &flags[tid * 32];
    while (__hip_atomic_load(f, __ATOMIC_ACQUIRE, __HIP_MEMORY_SCOPE_AGENT) < ep)
      __builtin_amdgcn_s_sleep(1);
    __syncthreads();
    if (tid == 0) {
      __threadfence();
      __hip_atomic_store(epoch, ep, __ATOMIC_RELEASE, __HIP_MEMORY_SCOPE_AGENT);
      __threadfence();
    }
  } else {
    if (tid == 0) {
      __threadfence();
      __hip_atomic_store(&flags[blockIdx.x * 32], ep, __ATOMIC_RELEASE, __HIP_MEMORY_SCOPE_AGENT);
      while (__hip_atomic_load(epoch, __ATOMIC_ACQUIRE, __HIP_MEMORY_SCOPE_AGENT) < ep)
        __builtin_amdgcn_s_sleep(4);
      __threadfence();
    }
  }
  __syncthreads();
}

// ---------------- fused persistent LSTM kernel ----------------
// grid = 256 blocks (1/CU), 256 threads (4 waves).
// Layer0: blocks 32x8 of [160 x 128], waves 2x2 of [80 x 64].
// Layer1: blocks 16x16 of [320 x 64], waves 4x1 of [80 x 64].
// A-fragments load DIRECTLY from global (L2-resident ring), 2-deep pipelined; B in LDS.
__global__ __launch_bounds__(256, 1) void lstm_fused(
    const int* __restrict__ x,
    const float* __restrict__ table0, const float* __restrict__ bias1,
    const unsigned short* __restrict__ Bp0, const unsigned short* __restrict__ Bp1,
    unsigned short* __restrict__ ring,   // ys0, 2 slots
    unsigned short* __restrict__ h1r,    // h1 bf16, 2 slots
    float* __restrict__ h1f,
    const float* __restrict__ dec_w, const float* __restrict__ dec_b,
    float* __restrict__ out, int* __restrict__ flags, int* __restrict__ epoch) {
  extern __shared__ char smem[];
  unsigned short* B0 = (unsigned short*)smem;            // [8 kc][8 nf][64][8]
  unsigned short* B1 = (unsigned short*)(smem + 65536);  // [16 kc][4 nf][64][8]

  const int tid  = threadIdx.x;
  const int lane = tid & 63;
  const int wid  = tid >> 6;
  const int l15  = lane & 15;
  const int lhi  = lane >> 4;
  const int bid  = blockIdx.x;

  const int mi0 = bid >> 3, ni0 = bid & 7;
  const int rows0 = mi0 * 160;
  const int wx0 = wid & 1, wy0 = wid >> 1;
  const int rw0 = wx0 * 80;

  const int mi1 = bid >> 4, ni1 = bid & 15;
  const int rows1 = mi1 * 320;
  const int rw1 = wid * 80;

  // stage both layers' weight tiles into LDS once (resident for all 80 steps)
  {
    const uint4* s0 = (const uint4*)(Bp0 + ni0 * 32768);
    uint4* d0 = (uint4*)B0;
    for (int i = tid; i < 4096; i += 256) d0[i] = s0[i];
    const uint4* s1 = (const uint4*)(Bp1 + ni1 * 32768);
    uint4* d1 = (uint4*)B1;
    for (int i = tid; i < 4096; i += 256) d1[i] = s1[i];
  }
  // zero the t=-1 h1 ring slot (slot 1) so the L1 K-loop is uniform (16 kc always).
  // Only the ni1==0 block of each row group writes; ordered before use by barrier(ep=1).
  if (ni1 == 0) {
    uint4 zz = {0, 0, 0, 0};
    uint4* z4 = (uint4*)(h1r + NBH + (size_t)rows1 * 256);
    for (int i = tid; i < 10240; i += 256) z4[i] = zz;
  }
  __syncthreads();

  f32x4 acc[5][4];
  float c0r[20], c1r[20];
  int ep = 0;

  for (int t = 0; t < T_SEQ; ++t) {
    // preload this step's x gathers (hidden under L0 GEMM)
    int xr[20];
#pragma unroll
    for (int m = 0; m < 5; ++m)
#pragma unroll
      for (int r = 0; r < 4; ++r)
        xr[m * 4 + r] = x[t * NB + rows0 + rw0 + m * 16 + lhi * 4 + r];

    // ================= layer 0 =================
#pragma unroll
    for (int m = 0; m < 5; ++m)
#pragma unroll
      for (int nf = 0; nf < 4; ++nf) acc[m][nf] = (f32x4)0.f;

    if (t > 0) {
      const unsigned short* Ar = ring + ((t - 1) & 1) * NBH;
      const unsigned short* ap = Ar + (size_t)(rows0 + rw0 + l15) * 256 + lhi * 8;
      bf16x8 aA[5], aB[5];
#pragma unroll
      for (int m = 0; m < 5; ++m) aA[m] = *(const bf16x8*)(ap + m * 4096);
#pragma unroll
      for (int kc = 0; kc < 8; ++kc) {
        const bf16x8* ac = (kc & 1) ? aB : aA;
        bf16x8*       an = (kc & 1) ? aA : aB;
        if (kc < 7) {
#pragma unroll
          for (int m = 0; m < 5; ++m)
            an[m] = *(const bf16x8*)(ap + (kc + 1) * 32 + m * 4096);
        }
#pragma unroll
        for (int nf = 0; nf < 4; ++nf) {
          bf16x8 b = *(const bf16x8*)(B0 + ((kc * 8 + wy0 * 4 + nf) * 64 + lane) * 8);
#pragma unroll
          for (int m = 0; m < 5; ++m)
            acc[m][nf] = __builtin_amdgcn_mfma_f32_16x16x32_bf16(ac[m], b, acc[m][nf], 0, 0, 0);
        }
      }
    }
    // epilogue L0: gates -> (c,h); c in regs; h -> ring[t&1] (bf16)
    {
      unsigned short* rw_ = ring + (t & 1) * NBH;
      const int jg = ni0 * 32 + wy0 * 16 + l15;
      const int tb_base = ni0 * 128 + wy0 * 64 + l15;
#pragma unroll
      for (int m = 0; m < 5; ++m) {
#pragma unroll
        for (int r = 0; r < 4; ++r) {
          int rowg = rows0 + rw0 + m * 16 + lhi * 4 + r;
          const float* tb = table0 + xr[m * 4 + r] * 1024 + tb_base;
          float gi = acc[m][0][r] + tb[0];
          float gf = acc[m][1][r] + tb[16];
          float gg = acc[m][2][r] + tb[32];
          float go = acc[m][3][r] + tb[48];
          float cold = (t > 0) ? c0r[m * 4 + r] : 0.f;
          float cn = sigm(gf) * cold + sigm(gi) * tanh_(gg);
          c0r[m * 4 + r] = cn;
          float h = sigm(go) * tanh_(cn);
          rw_[rowg * 256 + jg] = f2bf(h);
        }
      }
    }
    ++ep;
    gbar(flags, epoch, ep);   // single barrier per step orders all ring/h1r hazards

    // ================= layer 1 =================
#pragma unroll
    for (int m = 0; m < 5; ++m)
#pragma unroll
      for (int nf = 0; nf < 4; ++nf) acc[m][nf] = (f32x4)0.f;

    {
      const unsigned short* ringr = ring + (t & 1) * NBH;
      const unsigned short* h1old = h1r + ((t + 1) & 1) * NBH;  // (t-1)&1
      const unsigned short* apR = ringr + (size_t)(rows1 + rw1 + l15) * 256 + lhi * 8;
      const unsigned short* apH = h1old + (size_t)(rows1 + rw1 + l15) * 256 + lhi * 8;
      bf16x8 aA[5], aB[5];
#pragma unroll
      for (int m = 0; m < 5; ++m) aA[m] = *(const bf16x8*)(apR + m * 4096);
#pragma unroll
      for (int kc = 0; kc < 16; ++kc) {
        const bf16x8* ac = (kc & 1) ? aB : aA;
        bf16x8*       an = (kc & 1) ? aA : aB;
        if (kc < 15) {
          const int kn = kc + 1;
          const unsigned short* src = (kn < 8) ? (apR + kn * 32) : (apH + (kn - 8) * 32);
#pragma unroll
          for (int m = 0; m < 5; ++m)
            an[m] = *(const bf16x8*)(src + m * 4096);
        }
#pragma unroll
        for (int nf = 0; nf < 4; ++nf) {
          bf16x8 b = *(const bf16x8*)(B1 + ((kc * 4 + nf) * 64 + lane) * 8);
#pragma unroll
          for (int m = 0; m < 5; ++m)
            acc[m][nf] = __builtin_amdgcn_mfma_f32_16x16x32_bf16(ac[m], b, acc[m][nf], 0, 0, 0);
        }
      }
    }
    // epilogue L1
    {
      unsigned short* h1w = h1r + (t & 1) * NBH;
      const int jg = ni1 * 16 + l15;
      const float* bb = bias1 + ni1 * 64 + l15;
#pragma unroll
      for (int m = 0; m < 5; ++m) {
#pragma unroll
        for (int r = 0; r < 4; ++r) {
          int rowg = rows1 + rw1 + m * 16 + lhi * 4 + r;
          float gi = acc[m][0][r] + bb[0];
          float gf = acc[m][1][r] + bb[16];
          float gg = acc[m][2][r] + bb[32];
          float go = acc[m][3][r] + bb[48];
          float cold = (t > 0) ? c1r[m * 4 + r] : 0.f;
          float cn = sigm(gf) * cold + sigm(gi) * tanh_(gg);
          c1r[m * 4 + r] = cn;
          float h = sigm(go) * tanh_(cn);
          h1w[rowg * 256 + jg] = f2bf(h);
          if (t == T_SEQ - 1) h1f[rowg * 256 + jg] = h;  // f32 for decoder
        }
      }
    }
    // no trailing barrier: next iteration's barrier orders all remaining hazards
  }

  ++ep;
  gbar(flags, epoch, ep);   // h1f complete

  // ================= decoder: out[64][100] = flat[64][20480] @ dec_w^T + dec_b ========
  if (bid < NVOC) {
    const int v = bid;
    float dacc[64];
#pragma unroll
    for (int r = 0; r < 64; ++r) dacc[r] = 0.f;
    for (int q = tid; q < 20480; q += 256) {
      float w = dec_w[(size_t)v * 20480 + q];
      const float* fp = h1f + q;
#pragma unroll
      for (int r = 0; r < 64; ++r) dacc[r] = fmaf(fp[r * 20480], w, dacc[r]);
    }
    float* red = (float*)smem;   // B0 area is dead now
    __syncthreads();
#pragma unroll
    for (int r = 0; r < 64; ++r) {
      float s = dacc[r];
      for (int off = 32; off > 0; off >>= 1) s += __shfl_down(s, off, 64);
      if (lane == 0) red[wid * 64 + r] = s;
    }
    __syncthreads();
    if (tid < 64) {
      float s = red[tid] + red[64 + tid] + red[128 + tid] + red[192 + tid];
      out[tid * 100 + v] = s + dec_b[v];
    }
  }
}

// ---------------- host launch ----------------
extern "C" void kernel_launch(void* const* d_in, const int* in_sizes, int n_in,
                              void* d_out, int out_size, void* d_ws, size_t ws_size,
                              hipStream_t stream) {
  const int*   x     = (const int*)d_in[0];
  const float* emb   = (const float*)d_in[1];
  const float* w_ih0 = (const float*)d_in[2];
  const float* w_hh0 = (const float*)d_in[3];
  const float* b_ih0 = (const float*)d_in[4];
  const float* b_hh0 = (const float*)d_in[5];
  const float* w_ih1 = (const float*)d_in[6];
  const float* w_hh1 = (const float*)d_in[7];
  const float* b_ih1 = (const float*)d_in[8];
  const float* b_hh1 = (const float*)d_in[9];
  const float* dec_w = (const float*)d_in[10];
  const float* dec_b = (const float*)d_in[11];
  float* out = (float*)d_out;
  char* ws = (char*)d_ws;

  float*          table0 = (float*)(ws + OFF_TABLE0);
  float*          bias1  = (float*)(ws + OFF_BIAS1);
  unsigned short* Bp0    = (unsigned short*)(ws + OFF_BP0);
  unsigned short* Bp1    = (unsigned short*)(ws + OFF_BP1);
  unsigned short* ring   = (unsigned short*)(ws + OFF_RING);
  unsigned short* h1r    = (unsigned short*)(ws + OFF_H1R);
  float*          h1f    = (float*)(ws + OFF_H1F);
  int*            flags  = (int*)(ws + OFF_FLAGS);
  int*            epoch  = (int*)(ws + OFF_EPOCH);

  hipMemsetAsync(flags, 0, 32768 + 128, stream);  // flags + epoch
  prep_kernel<<<3476, 256, 0, stream>>>(emb, w_ih0, w_hh0, b_ih0, b_hh0,
                                        w_ih1, w_hh1, b_ih1, b_hh1,
                                        table0, bias1, Bp0, Bp1);
  hipFuncSetAttribute((const void*)lstm_fused,
                      hipFuncAttributeMaxDynamicSharedMemorySize, SMEM_BYTES);
  lstm_fused<<<256, 256, SMEM_BYTES, stream>>>(x, table0, bias1, Bp0, Bp1,
                                               ring, h1r, h1f, dec_w, dec_b, out,
                                               flags, epoch);
}